// Round 3
// baseline (200.344 us; speedup 1.0000x reference)
//
#include <hip/hip_runtime.h>
#include <hip/hip_cooperative_groups.h>
#include <math.h>

namespace cg = cooperative_groups;

// SurvLoss: Cox partial-likelihood loss with tie grouping.
// |Y| is an integer in [1,2000]; sorted order is -2000..-1,1..2000, so
//   loss2 = sum_t n_events(t) * log(negExpTotal + prefix_{u<=t} posExp(u))
//   loss1 = sum(Yhat * [Y>0]);  obs = count(Y>0)
// => 2000-bucket histogram + tiny double-precision scan. No sort.
//
// R3: single cooperative kernel (removes memset + 2 dispatch boundaries;
// dispatch gaps were a big share of the ~40 us controllable budget).
// Histogram packed into u64: count in bits [44:63], exp-sum as 2^-20
// fixed point in bits [0:43] -> one LDS atomic per positive sample
// (was two), non-atomic deterministic merge, no zero-init of ws needed.

#define NBLK 512
#define NT   256
#define NH   2048
#define CNT_SHIFT 44
#define FP_SCALE  1048576.0f            // 2^20
#define FP_INV    (1.0 / 1048576.0)
#define FP_MASK   ((1ULL << CNT_SHIFT) - 1)

__global__ __launch_bounds__(NT, 2) void surv_all(
    const float* __restrict__ Yhat, const float* __restrict__ Y, int n4,
    unsigned long long* __restrict__ Hist,     // NBLK x NH packed u64
    double* __restrict__ negPart,              // NBLK
    double* __restrict__ loss1Part,            // NBLK
    unsigned long long* __restrict__ obsPart,  // NBLK
    unsigned long long* __restrict__ gHist,    // NH merged
    float* __restrict__ out)
{
    cg::grid_group grid = cg::this_grid();
    const int tid = threadIdx.x;

    // ---------------- phase 1: per-block packed histogram ----------------
    __shared__ unsigned long long sHist[NH];
    for (int i = tid; i < NH; i += NT) sHist[i] = 0ull;
    __syncthreads();

    float negSum = 0.f, loss1 = 0.f;
    unsigned int obs = 0;
    const float4* __restrict__ Y4 = (const float4*)Y;
    const float4* __restrict__ H4 = (const float4*)Yhat;
    for (int i = blockIdx.x * NT + tid; i < n4; i += NBLK * NT) {
        float4 y = Y4[i];
        float4 h = H4[i];
        float ys[4] = {y.x, y.y, y.z, y.w};
        float hs[4] = {h.x, h.y, h.z, h.w};
        #pragma unroll
        for (int c = 0; c < 4; ++c) {
            float e = __expf(hs[c]);
            if (ys[c] > 0.f) {
                int t = (int)ys[c];  // t in [1,2000] < NH
                unsigned long long v = (1ULL << CNT_SHIFT) |
                    (unsigned long long)(e * FP_SCALE + 0.5f);
                atomicAdd(&sHist[t], v);   // one LDS atomic per event sample
                loss1 += hs[c];
                obs += 1u;
            } else {
                negSum += e;
            }
        }
    }

    // wave (64-lane) reduce of scalars
    #pragma unroll
    for (int off = 32; off > 0; off >>= 1) {
        negSum += __shfl_down(negSum, off);
        loss1  += __shfl_down(loss1, off);
        obs    += __shfl_down(obs, off);
    }
    __shared__ float wNeg[NT / 64], wL1[NT / 64];
    __shared__ unsigned int wObs[NT / 64];
    const int lane = tid & 63, wid = tid >> 6;
    if (lane == 0) { wNeg[wid] = negSum; wL1[wid] = loss1; wObs[wid] = obs; }
    __syncthreads();  // also completes all LDS hist atomics
    if (tid == 0) {
        double nn = 0.0, ll = 0.0; unsigned long long oo = 0ull;
        #pragma unroll
        for (int w = 0; w < NT / 64; ++w) {
            nn += (double)wNeg[w]; ll += (double)wL1[w]; oo += wObs[w];
        }
        negPart[blockIdx.x] = nn;
        loss1Part[blockIdx.x] = ll;
        obsPart[blockIdx.x] = oo;
    }
    // non-atomic coalesced dump of this block's histogram row
    unsigned long long* __restrict__ myRow = Hist + (size_t)blockIdx.x * NH;
    for (int i = tid; i < NH; i += NT) myRow[i] = sHist[i];

    grid.sync();

    // ------------- phase 2: merge 512 rows -> gHist (256 blocks) ----------
    if (blockIdx.x < 256) {
        const int colBase = blockIdx.x << 3;   // 8 columns per block
        const int col = tid & 7;
        const int rg  = tid >> 3;              // 32 row-groups
        unsigned long long s = 0ull;
        for (int r = rg; r < NBLK; r += 32)
            s += Hist[(size_t)r * NH + colBase + col];
        __shared__ unsigned long long red[32][8];
        red[rg][col] = s;
        __syncthreads();
        if (tid < 8) {
            unsigned long long tot = 0ull;
            #pragma unroll
            for (int g = 0; g < 32; ++g) tot += red[g][tid];
            gHist[colBase + tid] = tot;        // plain store, deterministic
        }
    }

    grid.sync();

    // ------------- phase 3: scan + log + final scalar (block 0) -----------
    if (blockIdx.x == 0) {
        __shared__ double sA[NT];

        double nP = negPart[tid] + negPart[tid + NT];
        double lP = loss1Part[tid] + loss1Part[tid + NT];
        double oP = (double)(obsPart[tid] + obsPart[tid + NT]);

        sA[tid] = nP; __syncthreads();
        for (int off = NT / 2; off > 0; off >>= 1) { if (tid < off) sA[tid] += sA[tid + off]; __syncthreads(); }
        const double negTotal = sA[0]; __syncthreads();

        sA[tid] = lP; __syncthreads();
        for (int off = NT / 2; off > 0; off >>= 1) { if (tid < off) sA[tid] += sA[tid + off]; __syncthreads(); }
        const double loss1T = sA[0]; __syncthreads();

        sA[tid] = oP; __syncthreads();
        for (int off = NT / 2; off > 0; off >>= 1) { if (tid < off) sA[tid] += sA[tid + off]; __syncthreads(); }
        const double obsT = sA[0]; __syncthreads();

        // each thread owns 8 consecutive buckets (ascending t across threads)
        const int C = NH / NT;  // 8
        double pe[C]; unsigned int ev[C];
        double csum = 0.0;
        const int base = tid * C;
        #pragma unroll
        for (int j = 0; j < C; ++j) {
            unsigned long long hx = gHist[base + j];
            ev[j] = (unsigned int)(hx >> CNT_SHIFT);
            pe[j] = (double)(hx & FP_MASK) * FP_INV;
            csum += pe[j];
        }

        // Hillis-Steele inclusive scan of per-thread chunk sums (double)
        sA[tid] = csum; __syncthreads();
        for (int off = 1; off < NT; off <<= 1) {
            double add = (tid >= off) ? sA[tid - off] : 0.0;
            __syncthreads();
            sA[tid] += add;
            __syncthreads();
        }
        const double excl = sA[tid] - csum;
        __syncthreads();

        double prefix = negTotal + excl;
        double loss2 = 0.0;
        #pragma unroll
        for (int j = 0; j < C; ++j) {
            prefix += pe[j];
            if (ev[j]) loss2 += (double)ev[j] * log(prefix);
        }

        sA[tid] = loss2; __syncthreads();
        for (int off = NT / 2; off > 0; off >>= 1) { if (tid < off) sA[tid] += sA[tid + off]; __syncthreads(); }
        if (tid == 0) out[0] = (float)((sA[0] - loss1T) / obsT);
    }
}

extern "C" void kernel_launch(void* const* d_in, const int* in_sizes, int n_in,
                              void* d_out, int out_size, void* d_ws, size_t ws_size,
                              hipStream_t stream)
{
    const float* Yhat = (const float*)d_in[0];
    const float* Y    = (const float*)d_in[1];
    int n4 = in_sizes[0] / 4;

    char* ws = (char*)d_ws;
    unsigned long long* Hist  = (unsigned long long*)ws;              // 8 MB
    char* tail = ws + (size_t)NBLK * NH * 8;
    unsigned long long* gHist = (unsigned long long*)tail;            // 16 KB
    double* negPart           = (double*)(tail + NH * 8);
    double* loss1Part         = (double*)(tail + NH * 8 + NBLK * 8);
    unsigned long long* obsPart = (unsigned long long*)(tail + NH * 8 + 2 * NBLK * 8);
    float* out = (float*)d_out;

    // every workspace word we read is written first within the kernel
    // (Hist rows, gHist, partials) -> no zero-init, no memset node.
    void* args[] = {(void*)&Yhat, (void*)&Y, (void*)&n4, (void*)&Hist,
                    (void*)&negPart, (void*)&loss1Part, (void*)&obsPart,
                    (void*)&gHist, (void*)&out};
    hipLaunchCooperativeKernel((void*)surv_all, dim3(NBLK), dim3(NT),
                               args, 0, stream);
}

// Round 4
// 110.783 us; speedup vs baseline: 1.8084x; 1.8084x over previous
//
#include <hip/hip_runtime.h>
#include <math.h>

// SurvLoss: Cox partial-likelihood loss with tie grouping.
// |Y| is an integer in [1,2000]; sorted order is -2000..-1,1..2000, so
//   loss2 = sum_t n_events(t) * log(negExpTotal + prefix_{u<=t} posExp(u))
//   loss1 = sum(Yhat * [Y>0]);  obs = count(Y>0)
// => 2000-bucket histogram + tiny double-precision scan. No sort.
//
// R4: two regular dispatches, no memset node, no cooperative launch.
//  - R3 lesson: u64 LDS atomicAdd + grid.sync() => 120 us latency-bound
//    kernel (VALUBusy 1.9%). Reverted to native u32/f32 LDS atomics.
//  - hist kernel zeroes the done-counter (stream order covers kernel 2).
//  - merge kernel uses the threadfence-reduction "last block" pattern so
//    the 2048-bucket double-precision scan+log rides in the same dispatch.

#define NBLK 512
#define NT   256
#define NH   2048
#define MBLK (NH / 16)   // 128 merge blocks, 16 columns each

__global__ __launch_bounds__(NT) void surv_hist(
    const float* __restrict__ Yhat, const float* __restrict__ Y, int n4,
    float* __restrict__ Exp,                   // NBLK x NH f32 row dumps
    unsigned short* __restrict__ Evt,          // NBLK x NH u16 row dumps
    double* __restrict__ negPart, double* __restrict__ loss1Part,
    unsigned long long* __restrict__ obsPart,
    unsigned int* __restrict__ cnt)
{
    // zero the completion counter for kernel 2 (stream order => visible)
    if (blockIdx.x == 0 && threadIdx.x == 0) *cnt = 0u;

    __shared__ float sExp[NH];
    __shared__ unsigned int sEvt[NH];
    for (int i = threadIdx.x; i < NH; i += NT) { sExp[i] = 0.f; sEvt[i] = 0u; }
    __syncthreads();

    float negSum = 0.f, loss1 = 0.f;
    unsigned int obs = 0;

    const float4* __restrict__ Y4 = (const float4*)Y;
    const float4* __restrict__ H4 = (const float4*)Yhat;
    const int stride = NBLK * NT;
    for (int i = blockIdx.x * NT + threadIdx.x; i < n4; i += 2 * stride) {
        #pragma unroll
        for (int u = 0; u < 2; ++u) {
            int idx = i + u * stride;
            if (idx >= n4) break;
            float4 y = Y4[idx];
            float4 h = H4[idx];
            float ys[4] = {y.x, y.y, y.z, y.w};
            float hs[4] = {h.x, h.y, h.z, h.w};
            #pragma unroll
            for (int c = 0; c < 4; ++c) {
                float e = __expf(hs[c]);
                if (ys[c] > 0.f) {
                    int t = (int)ys[c];            // t in [1,2000] < NH
                    atomicAdd(&sExp[t], e);        // native ds f32 atomic
                    atomicAdd(&sEvt[t], 1u);       // native ds u32 atomic
                    loss1 += hs[c];
                    obs += 1u;
                } else {
                    negSum += e;
                }
            }
        }
    }

    // wave (64-lane) reduce of scalars
    #pragma unroll
    for (int off = 32; off > 0; off >>= 1) {
        negSum += __shfl_down(negSum, off);
        loss1  += __shfl_down(loss1, off);
        obs    += __shfl_down(obs, off);
    }
    __shared__ float wNeg[NT / 64], wL1[NT / 64];
    __shared__ unsigned int wObs[NT / 64];
    const int lane = threadIdx.x & 63, wid = threadIdx.x >> 6;
    if (lane == 0) { wNeg[wid] = negSum; wL1[wid] = loss1; wObs[wid] = obs; }
    __syncthreads();  // also completes all LDS hist atomics
    if (threadIdx.x == 0) {
        double nn = 0.0, ll = 0.0; unsigned long long oo = 0ull;
        #pragma unroll
        for (int w = 0; w < NT / 64; ++w) {
            nn += (double)wNeg[w]; ll += (double)wL1[w]; oo += wObs[w];
        }
        negPart[blockIdx.x] = nn;
        loss1Part[blockIdx.x] = ll;
        obsPart[blockIdx.x] = oo;
    }

    // non-atomic coalesced dump of this block's histogram row
    float* __restrict__ myExp = Exp + (size_t)blockIdx.x * NH;
    unsigned short* __restrict__ myEvt = Evt + (size_t)blockIdx.x * NH;
    for (int i = threadIdx.x; i < NH; i += NT) {
        myExp[i] = sExp[i];
        myEvt[i] = (unsigned short)sEvt[i];   // per-block count <= 8192
    }
}

// 128 blocks: merge 512 rows -> gExp/gEvt; last finishing block does the
// double-precision scan + log + final scalar (threadfence reduction).
__global__ __launch_bounds__(NT) void surv_mergefinal(
    const float* __restrict__ Exp, const unsigned short* __restrict__ Evt,
    float* __restrict__ gExp, unsigned int* __restrict__ gEvt,
    const double* __restrict__ negPart, const double* __restrict__ loss1Part,
    const unsigned long long* __restrict__ obsPart,
    unsigned int* __restrict__ cnt, float* __restrict__ out)
{
    const int tid = threadIdx.x;
    const int colBase = blockIdx.x * 16;
    const int col = tid & 15;
    const int rg  = tid >> 4;                 // 16 row-groups

    float se = 0.f;
    unsigned int ce = 0u;
    for (int r = rg; r < NBLK; r += 16) {
        se += Exp[(size_t)r * NH + colBase + col];
        ce += Evt[(size_t)r * NH + colBase + col];
    }
    __shared__ float rE[16][17];
    __shared__ unsigned int rC[16][17];
    rE[rg][col] = se;
    rC[rg][col] = ce;
    __syncthreads();
    if (tid < 16) {
        float ts = 0.f; unsigned int tc = 0u;
        #pragma unroll
        for (int g = 0; g < 16; ++g) { ts += rE[g][tid]; tc += rC[g][tid]; }
        gExp[colBase + tid] = ts;             // plain store, deterministic
        gEvt[colBase + tid] = tc;
    }

    // last-block election (device-scope release/acquire for cross-XCD)
    __shared__ int sLast;
    __syncthreads();
    __threadfence();
    if (tid == 0) {
        unsigned int old = atomicAdd(cnt, 1u);
        sLast = (old == MBLK - 1) ? 1 : 0;
    }
    __syncthreads();
    if (!sLast) return;
    __threadfence();  // acquire: see all blocks' gExp/gEvt stores

    // ---------------- final phase (one block of 256 threads) --------------
    __shared__ double sA[NT];

    double nP = negPart[tid] + negPart[tid + NT];
    double lP = loss1Part[tid] + loss1Part[tid + NT];
    double oP = (double)(obsPart[tid] + obsPart[tid + NT]);

    sA[tid] = nP; __syncthreads();
    for (int off = NT / 2; off > 0; off >>= 1) { if (tid < off) sA[tid] += sA[tid + off]; __syncthreads(); }
    const double negTotal = sA[0]; __syncthreads();

    sA[tid] = lP; __syncthreads();
    for (int off = NT / 2; off > 0; off >>= 1) { if (tid < off) sA[tid] += sA[tid + off]; __syncthreads(); }
    const double loss1T = sA[0]; __syncthreads();

    sA[tid] = oP; __syncthreads();
    for (int off = NT / 2; off > 0; off >>= 1) { if (tid < off) sA[tid] += sA[tid + off]; __syncthreads(); }
    const double obsT = sA[0]; __syncthreads();

    // each thread owns 8 consecutive buckets (ascending t across threads)
    const int C = NH / NT;  // 8
    double pe[C]; unsigned int ev[C];
    double csum = 0.0;
    const int base = tid * C;
    #pragma unroll
    for (int j = 0; j < C; ++j) {
        pe[j] = (double)gExp[base + j];
        ev[j] = gEvt[base + j];
        csum += pe[j];
    }

    // Hillis-Steele inclusive scan of per-thread chunk sums (double)
    sA[tid] = csum; __syncthreads();
    for (int off = 1; off < NT; off <<= 1) {
        double add = (tid >= off) ? sA[tid - off] : 0.0;
        __syncthreads();
        sA[tid] += add;
        __syncthreads();
    }
    const double excl = sA[tid] - csum;
    __syncthreads();

    double prefix = negTotal + excl;
    double loss2 = 0.0;
    #pragma unroll
    for (int j = 0; j < C; ++j) {
        prefix += pe[j];
        if (ev[j]) loss2 += (double)ev[j] * log(prefix);
    }

    sA[tid] = loss2; __syncthreads();
    for (int off = NT / 2; off > 0; off >>= 1) { if (tid < off) sA[tid] += sA[tid + off]; __syncthreads(); }
    if (tid == 0) out[0] = (float)((sA[0] - loss1T) / obsT);
}

extern "C" void kernel_launch(void* const* d_in, const int* in_sizes, int n_in,
                              void* d_out, int out_size, void* d_ws, size_t ws_size,
                              hipStream_t stream)
{
    const float* Yhat = (const float*)d_in[0];
    const float* Y    = (const float*)d_in[1];
    const int n4 = in_sizes[0] / 4;

    char* ws = (char*)d_ws;
    float* Exp          = (float*)ws;                                  // 4 MB
    unsigned short* Evt = (unsigned short*)(ws + (size_t)NBLK * NH * 4); // 2 MB
    char* tail          = ws + (size_t)NBLK * NH * 6;
    float* gExp         = (float*)tail;                                // 8 KB
    unsigned int* gEvt  = (unsigned int*)(tail + NH * 4);              // 8 KB
    double* negPart     = (double*)(tail + NH * 8);                    // 4 KB
    double* loss1Part   = (double*)(tail + NH * 8 + NBLK * 8);         // 4 KB
    unsigned long long* obsPart =
        (unsigned long long*)(tail + NH * 8 + 2 * NBLK * 8);           // 4 KB
    unsigned int* cnt   = (unsigned int*)(tail + NH * 8 + 3 * NBLK * 8);

    surv_hist<<<NBLK, NT, 0, stream>>>(Yhat, Y, n4, Exp, Evt,
                                       negPart, loss1Part, obsPart, cnt);
    surv_mergefinal<<<MBLK, NT, 0, stream>>>(Exp, Evt, gExp, gEvt,
                                             negPart, loss1Part, obsPart,
                                             cnt, (float*)d_out);
}

// Round 5
// 110.540 us; speedup vs baseline: 1.8124x; 1.0022x over previous
//
#include <hip/hip_runtime.h>
#include <math.h>

// SurvLoss: Cox partial-likelihood loss with tie grouping.
// |Y| is an integer in [1,2000]; sorted order is -2000..-1,1..2000, so
//   loss2 = sum_t n_events(t) * log(negExpTotal + prefix_{u<=t} posExp(u))
//   loss1 = sum(Yhat * [Y>0]);  obs = count(Y>0)
// => 2000-bucket histogram + tiny double-precision scan. No sort.
//
// R5: leanest 2-dispatch variant. Controllable kernel time is ~10 us against
// a ~70+ us harness window (256 MiB ws poison fill = 43.5 us measured, input
// restore ~11 us, graph overheads); R2 (97.4) vs R4 (110.8) delta is noise,
// not structure. This round: R2's simple hist loop (no unroll), R4's 2-node
// shape, to confirm the floor before declaring ceiling.

#define NBLK 512
#define NT   256
#define NH   2048
#define MBLK (NH / 16)   // 128 merge blocks, 16 columns each

__global__ __launch_bounds__(NT) void surv_hist(
    const float* __restrict__ Yhat, const float* __restrict__ Y, int n4,
    float* __restrict__ Exp,                   // NBLK x NH f32 row dumps
    unsigned short* __restrict__ Evt,          // NBLK x NH u16 row dumps
    double* __restrict__ negPart, double* __restrict__ loss1Part,
    unsigned long long* __restrict__ obsPart,
    unsigned int* __restrict__ cnt)
{
    // zero the completion counter for kernel 2 (stream order => visible)
    if (blockIdx.x == 0 && threadIdx.x == 0) *cnt = 0u;

    __shared__ float sExp[NH];
    __shared__ unsigned int sEvt[NH];
    for (int i = threadIdx.x; i < NH; i += NT) { sExp[i] = 0.f; sEvt[i] = 0u; }
    __syncthreads();

    float negSum = 0.f, loss1 = 0.f;
    unsigned int obs = 0;

    const float4* __restrict__ Y4 = (const float4*)Y;
    const float4* __restrict__ H4 = (const float4*)Yhat;
    for (int i = blockIdx.x * NT + threadIdx.x; i < n4; i += NBLK * NT) {
        float4 y = Y4[i];
        float4 h = H4[i];
        float ys[4] = {y.x, y.y, y.z, y.w};
        float hs[4] = {h.x, h.y, h.z, h.w};
        #pragma unroll
        for (int c = 0; c < 4; ++c) {
            float e = __expf(hs[c]);
            if (ys[c] > 0.f) {
                int t = (int)ys[c];            // t in [1,2000] < NH
                atomicAdd(&sExp[t], e);        // native ds f32 atomic
                atomicAdd(&sEvt[t], 1u);       // native ds u32 atomic
                loss1 += hs[c];
                obs += 1u;
            } else {
                negSum += e;
            }
        }
    }

    // wave (64-lane) reduce of scalars
    #pragma unroll
    for (int off = 32; off > 0; off >>= 1) {
        negSum += __shfl_down(negSum, off);
        loss1  += __shfl_down(loss1, off);
        obs    += __shfl_down(obs, off);
    }
    __shared__ float wNeg[NT / 64], wL1[NT / 64];
    __shared__ unsigned int wObs[NT / 64];
    const int lane = threadIdx.x & 63, wid = threadIdx.x >> 6;
    if (lane == 0) { wNeg[wid] = negSum; wL1[wid] = loss1; wObs[wid] = obs; }
    __syncthreads();  // also completes all LDS hist atomics
    if (threadIdx.x == 0) {
        double nn = 0.0, ll = 0.0; unsigned long long oo = 0ull;
        #pragma unroll
        for (int w = 0; w < NT / 64; ++w) {
            nn += (double)wNeg[w]; ll += (double)wL1[w]; oo += wObs[w];
        }
        negPart[blockIdx.x] = nn;
        loss1Part[blockIdx.x] = ll;
        obsPart[blockIdx.x] = oo;
    }

    // non-atomic coalesced dump of this block's histogram row
    float* __restrict__ myExp = Exp + (size_t)blockIdx.x * NH;
    unsigned short* __restrict__ myEvt = Evt + (size_t)blockIdx.x * NH;
    for (int i = threadIdx.x; i < NH; i += NT) {
        myExp[i] = sExp[i];
        myEvt[i] = (unsigned short)sEvt[i];   // per-block count <= 8192
    }
}

// 128 blocks: merge 512 rows -> gExp/gEvt; last finishing block does the
// double-precision scan + log + final scalar (threadfence reduction).
__global__ __launch_bounds__(NT) void surv_mergefinal(
    const float* __restrict__ Exp, const unsigned short* __restrict__ Evt,
    float* __restrict__ gExp, unsigned int* __restrict__ gEvt,
    const double* __restrict__ negPart, const double* __restrict__ loss1Part,
    const unsigned long long* __restrict__ obsPart,
    unsigned int* __restrict__ cnt, float* __restrict__ out)
{
    const int tid = threadIdx.x;
    const int colBase = blockIdx.x * 16;
    const int col = tid & 15;
    const int rg  = tid >> 4;                 // 16 row-groups

    float se = 0.f;
    unsigned int ce = 0u;
    for (int r = rg; r < NBLK; r += 16) {
        se += Exp[(size_t)r * NH + colBase + col];
        ce += Evt[(size_t)r * NH + colBase + col];
    }
    __shared__ float rE[16][17];
    __shared__ unsigned int rC[16][17];
    rE[rg][col] = se;
    rC[rg][col] = ce;
    __syncthreads();
    if (tid < 16) {
        float ts = 0.f; unsigned int tc = 0u;
        #pragma unroll
        for (int g = 0; g < 16; ++g) { ts += rE[g][tid]; tc += rC[g][tid]; }
        gExp[colBase + tid] = ts;             // plain store, deterministic
        gEvt[colBase + tid] = tc;
    }

    // last-block election (device-scope release/acquire for cross-XCD)
    __shared__ int sLast;
    __syncthreads();
    __threadfence();
    if (tid == 0) {
        unsigned int old = atomicAdd(cnt, 1u);
        sLast = (old == MBLK - 1) ? 1 : 0;
    }
    __syncthreads();
    if (!sLast) return;
    __threadfence();  // acquire: see all blocks' gExp/gEvt stores

    // ---------------- final phase (one block of 256 threads) --------------
    __shared__ double sA[NT];

    double nP = negPart[tid] + negPart[tid + NT];
    double lP = loss1Part[tid] + loss1Part[tid + NT];
    double oP = (double)(obsPart[tid] + obsPart[tid + NT]);

    sA[tid] = nP; __syncthreads();
    for (int off = NT / 2; off > 0; off >>= 1) { if (tid < off) sA[tid] += sA[tid + off]; __syncthreads(); }
    const double negTotal = sA[0]; __syncthreads();

    sA[tid] = lP; __syncthreads();
    for (int off = NT / 2; off > 0; off >>= 1) { if (tid < off) sA[tid] += sA[tid + off]; __syncthreads(); }
    const double loss1T = sA[0]; __syncthreads();

    sA[tid] = oP; __syncthreads();
    for (int off = NT / 2; off > 0; off >>= 1) { if (tid < off) sA[tid] += sA[tid + off]; __syncthreads(); }
    const double obsT = sA[0]; __syncthreads();

    // each thread owns 8 consecutive buckets (ascending t across threads)
    const int C = NH / NT;  // 8
    double pe[C]; unsigned int ev[C];
    double csum = 0.0;
    const int base = tid * C;
    #pragma unroll
    for (int j = 0; j < C; ++j) {
        pe[j] = (double)gExp[base + j];
        ev[j] = gEvt[base + j];
        csum += pe[j];
    }

    // Hillis-Steele inclusive scan of per-thread chunk sums (double)
    sA[tid] = csum; __syncthreads();
    for (int off = 1; off < NT; off <<= 1) {
        double add = (tid >= off) ? sA[tid - off] : 0.0;
        __syncthreads();
        sA[tid] += add;
        __syncthreads();
    }
    const double excl = sA[tid] - csum;
    __syncthreads();

    double prefix = negTotal + excl;
    double loss2 = 0.0;
    #pragma unroll
    for (int j = 0; j < C; ++j) {
        prefix += pe[j];
        if (ev[j]) loss2 += (double)ev[j] * log(prefix);
    }

    sA[tid] = loss2; __syncthreads();
    for (int off = NT / 2; off > 0; off >>= 1) { if (tid < off) sA[tid] += sA[tid + off]; __syncthreads(); }
    if (tid == 0) out[0] = (float)((sA[0] - loss1T) / obsT);
}

extern "C" void kernel_launch(void* const* d_in, const int* in_sizes, int n_in,
                              void* d_out, int out_size, void* d_ws, size_t ws_size,
                              hipStream_t stream)
{
    const float* Yhat = (const float*)d_in[0];
    const float* Y    = (const float*)d_in[1];
    const int n4 = in_sizes[0] / 4;

    char* ws = (char*)d_ws;
    float* Exp          = (float*)ws;                                  // 4 MB
    unsigned short* Evt = (unsigned short*)(ws + (size_t)NBLK * NH * 4); // 2 MB
    char* tail          = ws + (size_t)NBLK * NH * 6;
    float* gExp         = (float*)tail;                                // 8 KB
    unsigned int* gEvt  = (unsigned int*)(tail + NH * 4);              // 8 KB
    double* negPart     = (double*)(tail + NH * 8);                    // 4 KB
    double* loss1Part   = (double*)(tail + NH * 8 + NBLK * 8);         // 4 KB
    unsigned long long* obsPart =
        (unsigned long long*)(tail + NH * 8 + 2 * NBLK * 8);           // 4 KB
    unsigned int* cnt   = (unsigned int*)(tail + NH * 8 + 3 * NBLK * 8);

    surv_hist<<<NBLK, NT, 0, stream>>>(Yhat, Y, n4, Exp, Evt,
                                       negPart, loss1Part, obsPart, cnt);
    surv_mergefinal<<<MBLK, NT, 0, stream>>>(Exp, Evt, gExp, gEvt,
                                             negPart, loss1Part, obsPart,
                                             cnt, (float*)d_out);
}